// Round 3
// baseline (137.472 us; speedup 1.0000x reference)
//
#include <hip/hip_runtime.h>
#include <hip/hip_bf16.h>
#include <math.h>

// Problem constants: B=8, N=100, D=768, H=768, TH=24, T=577.
#define PB   8
#define PN   100
#define PD   768
#define PT   577
#define PTH  24
#define BN_TOT (PB * PN)       // 800 pooled rows
#define MPAD   832             // 800 padded to 26*32

typedef __attribute__((ext_vector_type(8))) short bf16x8;   // 8 bf16 (4 VGPRs)
typedef __attribute__((ext_vector_type(4))) float f32x4;

// ---------------------------------------------------------------------------
// Kernel 1 (fused): blocks 0..143   : x-prefix of feature map into SAT
//                   blocks 144..1295: W1 f32 -> W1T bf16 transpose
// SAT layout: [B][25][25][768] f32. SAT[b][Y][X][d] = sum_{y<Y,x<X} feat.
// ---------------------------------------------------------------------------
#define SATX_BLOCKS 144        // 8*24*192 threads / 256
#define CVT_BLOCKS  1152       // 24*24*2

__global__ __launch_bounds__(256) void prep_kernel(
    const float* __restrict__ patch,   // [B,577,768]
    const float* __restrict__ W1,      // [1536,768]
    float* __restrict__ SAT,
    __hip_bfloat16* __restrict__ W1T)
{
    __shared__ float tile[32][33];
    const int t = threadIdx.x;

    if (blockIdx.x < SATX_BLOCKS) {
        // ---- sat_x: one thread per (b, y, d4); float4 over d ----
        const int gid = blockIdx.x * 256 + t;       // 0..36863
        const int d4 = gid % 192;
        const int y  = (gid / 192) % PTH;
        const int b  = gid / (192 * PTH);

        const float4* src = (const float4*)(patch + ((size_t)(b * PT + 1 + y * PTH)) * PD) + d4;
        float4* dst = (float4*)(SAT + ((size_t)((b * 25) + (y + 1)) * 25) * PD) + d4;

        dst[0] = make_float4(0.f, 0.f, 0.f, 0.f);
        float4 acc = make_float4(0.f, 0.f, 0.f, 0.f);
#pragma unroll
        for (int X = 1; X <= PTH; ++X) {
            float4 v = src[(size_t)(X - 1) * 192];
            acc.x += v.x; acc.y += v.y; acc.z += v.z; acc.w += v.w;
            dst[(size_t)X * 192] = acc;
        }
    } else {
        // ---- cvt_w1t: W1T[n][k] = W1[k + 768*(n>=768)][n&767] ----
        const int bid = blockIdx.x - SATX_BLOCKS;   // 0..1151
        const int half = bid / 576;
        const int rem  = bid % 576;
        const int k0 = (rem / 24) * 32;
        const int n0 = (rem % 24) * 32;
        const int c  = t & 31;
        const int r4 = t >> 5;                      // 0..7

#pragma unroll
        for (int l = 0; l < 4; ++l) {
            int r = r4 + 8 * l;
            tile[r][c] = W1[(size_t)(half * PD + k0 + r) * PD + n0 + c];
        }
        __syncthreads();
#pragma unroll
        for (int l = 0; l < 4; ++l) {
            int r = r4 + 8 * l;                     // n-offset within tile
            W1T[(size_t)(half * PD + n0 + r) * PD + k0 + c] =
                __float2bfloat16(tile[c][r]);
        }
    }
}

// ---------------------------------------------------------------------------
// Kernel 2: y-prefix of SAT in place; float4 over d.  8*25*192 threads.
// ---------------------------------------------------------------------------
__global__ __launch_bounds__(256) void sat_y_kernel(float* __restrict__ SAT)
{
    const int gid = blockIdx.x * 256 + threadIdx.x;   // 0..38399
    const int d4 = gid % 192;
    const int X  = (gid / 192) % 25;
    const int b  = gid / (192 * 25);

    float4* col = (float4*)(SAT + ((size_t)(b * 25) * 25 + X) * PD) + d4;
    col[0] = make_float4(0.f, 0.f, 0.f, 0.f);
    float4 acc = make_float4(0.f, 0.f, 0.f, 0.f);
#pragma unroll
    for (int Y = 1; Y <= PTH; ++Y) {
        float4* p = col + (size_t)Y * 25 * 192;
        float4 v = *p;
        acc.x += v.x; acc.y += v.y; acc.z += v.z; acc.w += v.w;
        *p = acc;
    }
}

// ---------------------------------------------------------------------------
// Kernel 3: pooled rows via 4 SAT lookups; emit bf16 [832][768].
// Block = one row m; 192 threads, one float4 d-group each.
// ---------------------------------------------------------------------------
__global__ __launch_bounds__(192) void pool_sat_kernel(
    const float* __restrict__ SAT,
    const float* __restrict__ boxes,   // [800,4]
    const int*   __restrict__ img_h,
    const int*   __restrict__ img_w,
    __hip_bfloat16* __restrict__ pooledh)   // [832][768]
{
    const int m = blockIdx.x;          // 0..831
    const int t = threadIdx.x;         // 0..191
    short4* o = (short4*)(pooledh + (size_t)m * PD);

    if (m >= BN_TOT) {
        short4 z; z.x = 0; z.y = 0; z.z = 0; z.w = 0;
        o[t] = z;
        return;
    }

    const int b = m / PN;
    const float x1 = boxes[m * 4 + 0];
    const float y1 = boxes[m * 4 + 1];
    const float x2 = boxes[m * 4 + 2];
    const float y2 = boxes[m * 4 + 3];
    const float W  = (float)img_w[0];
    const float H  = (float)img_h[0];

    auto to_patch = [](float v, float size) -> int {
        float pix = floorf(v * size);
        float tt  = pix / size * (float)PTH;
        return (int)floorf(tt);
    };
    int px1 = min(max(to_patch(x1, W), 0), PTH - 1);
    int py1 = min(max(to_patch(y1, H), 0), PTH - 1);
    int px2 = min(max(to_patch(x2, W), 1), PTH);
    int py2 = min(max(to_patch(y2, H), 1), PTH);
    if (px2 <= px1) px2 = px1 + 1;
    if (py2 <= py1) py2 = py1 + 1;
    const float inv = 1.0f / (float)((px2 - px1) * (py2 - py1));

    const float* Sb = SAT + (size_t)b * 25 * 25 * PD;
    const float4 s22 = ((const float4*)(Sb + ((size_t)py2 * 25 + px2) * PD))[t];
    const float4 s12 = ((const float4*)(Sb + ((size_t)py1 * 25 + px2) * PD))[t];
    const float4 s21 = ((const float4*)(Sb + ((size_t)py2 * 25 + px1) * PD))[t];
    const float4 s11 = ((const float4*)(Sb + ((size_t)py1 * 25 + px1) * PD))[t];

    auto cvt = [](float f) -> short {
        __hip_bfloat16 h = __float2bfloat16(f);
        return *(short*)&h;
    };
    short4 r;
    r.x = cvt(((s22.x - s12.x) - (s21.x - s11.x)) * inv);
    r.y = cvt(((s22.y - s12.y) - (s21.y - s11.y)) * inv);
    r.z = cvt(((s22.z - s12.z) - (s21.z - s11.z)) * inv);
    r.w = cvt(((s22.w - s12.w) - (s21.w - s11.w)) * inv);
    o[t] = r;
}

// ---------------------------------------------------------------------------
// Kernel 4: bf16 MFMA GEMM.  C[832][1536] = A[832][768] * W1T^T.
// Tile 32(M) x 64(N); 2 waves; fragments direct from global (L2-resident).
// ---------------------------------------------------------------------------
__global__ __launch_bounds__(128) void gemm_mfma_kernel(
    const __hip_bfloat16* __restrict__ A,    // pooled bf16 [832][768]
    const __hip_bfloat16* __restrict__ Bt,   // W1T bf16 [1536][768]
    const float* __restrict__ b1,            // [768]
    float* __restrict__ C)                   // hab [832][1536]
{
    const int bn = blockIdx.x;               // 0..23
    const int bm = blockIdx.y;               // 0..25
    const int wave = threadIdx.x >> 6;       // 0..1
    const int lane = threadIdx.x & 63;
    const int lm = lane & 15;
    const int g  = lane >> 4;                // 0..3

    const int m0 = bm * 32;
    const int n0 = bn * 64 + wave * 32;

    const __hip_bfloat16* pa0 = A  + (size_t)(m0 + lm) * PD + g * 8;
    const __hip_bfloat16* pa1 = pa0 + (size_t)16 * PD;
    const __hip_bfloat16* pb0 = Bt + (size_t)(n0 + lm) * PD + g * 8;
    const __hip_bfloat16* pb1 = pb0 + (size_t)16 * PD;

    f32x4 acc00 = {}, acc01 = {}, acc10 = {}, acc11 = {};

#pragma unroll 4
    for (int k0 = 0; k0 < PD; k0 += 32) {
        bf16x8 a0 = *(const bf16x8*)(pa0 + k0);
        bf16x8 a1 = *(const bf16x8*)(pa1 + k0);
        bf16x8 b0 = *(const bf16x8*)(pb0 + k0);
        bf16x8 b1v = *(const bf16x8*)(pb1 + k0);
        acc00 = __builtin_amdgcn_mfma_f32_16x16x32_bf16(a0, b0,  acc00, 0, 0, 0);
        acc01 = __builtin_amdgcn_mfma_f32_16x16x32_bf16(a0, b1v, acc01, 0, 0, 0);
        acc10 = __builtin_amdgcn_mfma_f32_16x16x32_bf16(a1, b0,  acc10, 0, 0, 0);
        acc11 = __builtin_amdgcn_mfma_f32_16x16x32_bf16(a1, b1v, acc11, 0, 0, 0);
    }

    // C/D layout: col = lane&15, row = (lane>>4)*4 + reg
    const int rbase = g * 4;
#pragma unroll
    for (int r = 0; r < 4; ++r) {
        int row0 = m0 + rbase + r;
        int row1 = row0 + 16;
        int col0 = n0 + lm;
        int col1 = col0 + 16;
        float bb0 = (col0 < PD) ? b1[col0] : 0.0f;
        float bb1 = (col1 < PD) ? b1[col1] : 0.0f;
        C[(size_t)row0 * 1536 + col0] = acc00[r] + bb0;
        C[(size_t)row0 * 1536 + col1] = acc01[r] + bb1;
        C[(size_t)row1 * 1536 + col0] = acc10[r] + bb0;
        C[(size_t)row1 * 1536 + col1] = acc11[r] + bb1;
    }
}

// ---------------------------------------------------------------------------
// Kernel 5: out[b,i,j] = sigmoid( sum_h relu(ha'[i,h]+hb[j,h]) * W2[h] + b2 )
// Grid (jt=2, it=13, b=8); block 256.  8 ha rows register-resident per lane;
// each wave streams its j's (stride 4 within a 50-j half), software-pipelined.
// ---------------------------------------------------------------------------
__device__ __forceinline__ float rdot(const float4 A, const float4 C,
                                      const float4 W, float s) {
    s = fmaf(fmaxf(A.x + C.x, 0.f), W.x, s);
    s = fmaf(fmaxf(A.y + C.y, 0.f), W.y, s);
    s = fmaf(fmaxf(A.z + C.z, 0.f), W.z, s);
    s = fmaf(fmaxf(A.w + C.w, 0.f), W.w, s);
    return s;
}

__global__ __launch_bounds__(256) void pair_kernel(
    const float* __restrict__ hab,   // [832,1536]: [:,0:768]=ha+b1, [:,768:]=hb
    const float* __restrict__ W2,    // [768]
    const float* __restrict__ b2,    // [1]
    float* __restrict__ out)         // [B,N,N]
{
    const int jt = blockIdx.x;       // 0..1
    const int i0 = blockIdx.y * 8;   // 0,8,...,96
    const int b  = blockIdx.z;       // 0..7
    const int nrows = min(8, PN - i0);
    const int t = threadIdx.x;
    const int wave = t >> 6;
    const int lane = t & 63;

    const float4* w2v = (const float4*)W2;
    const float4 w0 = w2v[lane], w1 = w2v[lane + 64], w2r = w2v[lane + 128];
    const float bb2 = b2[0];

    float4 a[8][3];
#pragma unroll
    for (int i = 0; i < 8; ++i) {
        int row = b * PN + (i < nrows ? i0 + i : i0);
        const float4* ha = (const float4*)(hab + (size_t)row * 1536);
        a[i][0] = ha[lane]; a[i][1] = ha[lane + 64]; a[i][2] = ha[lane + 128];
    }

    const float4* hbbase = (const float4*)(hab + (size_t)(b * PN) * 1536) + 192;
    const int jend = jt * 50 + 50;
    int j = jt * 50 + wave;

    float4 h0, h1, h2;
    {
        const float4* hb = hbbase + (size_t)j * 384;
        h0 = hb[lane]; h1 = hb[lane + 64]; h2 = hb[lane + 128];
    }

    for (; j < jend; j += 4) {
        const float4 c0 = h0, c1 = h1, c2 = h2;
        const int jn = j + 4;
        if (jn < jend) {
            const float4* hb = hbbase + (size_t)jn * 384;
            h0 = hb[lane]; h1 = hb[lane + 64]; h2 = hb[lane + 128];
        }
        float acc[8];
#pragma unroll
        for (int i = 0; i < 8; ++i)
            acc[i] = rdot(a[i][2], c2, w2r, rdot(a[i][1], c1, w1, rdot(a[i][0], c0, w0, 0.f)));
#pragma unroll
        for (int i = 0; i < 8; ++i)
#pragma unroll
            for (int m = 32; m; m >>= 1)
                acc[i] += __shfl_xor(acc[i], m, 64);
        if (lane == 0) {
#pragma unroll
            for (int i = 0; i < 8; ++i)
                if (i < nrows)
                    out[(size_t)(b * PN + i0 + i) * PN + j] =
                        1.0f / (1.0f + expf(-(acc[i] + bb2)));
        }
    }
}

// ---------------------------------------------------------------------------
extern "C" void kernel_launch(void* const* d_in, const int* in_sizes, int n_in,
                              void* d_out, int out_size, void* d_ws, size_t ws_size,
                              hipStream_t stream) {
    const float* patch = (const float*)d_in[0];   // [8,577,768]
    const float* boxes = (const float*)d_in[1];   // [8,100,4]
    const float* W1    = (const float*)d_in[2];   // [1536,768]
    const float* b1    = (const float*)d_in[3];   // [768]
    const float* W2    = (const float*)d_in[4];   // [768]
    const float* b2    = (const float*)d_in[5];   // [1]
    const int*   img_h = (const int*)d_in[6];
    const int*   img_w = (const int*)d_in[7];
    float* out = (float*)d_out;

    // ws layout (bytes):
    //   SAT      f32 [8][25][25][768]  = 15,360,000
    //   pooledh  bf16 [832][768]       =  1,277,952
    //   W1T      bf16 [1536][768]      =  2,359,296
    //   hab      f32 [832][1536]       =  5,111,808
    char* wsb = (char*)d_ws;
    float*          SAT     = (float*)(wsb);
    __hip_bfloat16* pooledh = (__hip_bfloat16*)(wsb + 15360000);
    __hip_bfloat16* W1T     = (__hip_bfloat16*)(wsb + 15360000 + 1277952);
    float*          hab     = (float*)(wsb + 15360000 + 1277952 + 2359296);

    prep_kernel<<<SATX_BLOCKS + CVT_BLOCKS, 256, 0, stream>>>(patch, W1, SAT, W1T);
    sat_y_kernel<<<150, 256, 0, stream>>>(SAT);
    pool_sat_kernel<<<MPAD, 192, 0, stream>>>(SAT, boxes, img_h, img_w, pooledh);
    gemm_mfma_kernel<<<dim3(24, 26), 128, 0, stream>>>(pooledh, W1T, b1, hab);
    pair_kernel<<<dim3(2, 13, 8), 256, 0, stream>>>(hab, W2, b2, out);
}